// Round 3
// baseline (75.029 us; speedup 1.0000x reference)
//
#include <hip/hip_runtime.h>

using bf16x8 = __attribute__((ext_vector_type(8))) __bf16;
using f32x16 = __attribute__((ext_vector_type(16))) float;

#define BB 4
#define DD 64
#define LL 4096

// Kernel 1: x[b,l,d] = sum_k pe[b,k,l]*W[d,k] + bias[d];
// xs = bf16(x * sqrt(log2e)/ls)  (log2-domain pre-scale);
// h = 0.5*sum(xs_rounded^2)  -> MFMA dot - hi - hj is directly the exp2 arg.
__global__ __launch_bounds__(256) void prep_kernel(
    const float* __restrict__ pe,   // [B][D][L]
    const float* __restrict__ W,    // [D][D] row-major (out,in)
    const float* __restrict__ bias, // [D]
    const float* __restrict__ ls,   // scalar
    __bf16* __restrict__ xs,        // [B][L][D]
    float* __restrict__ h)          // [B][L]
{
    __shared__ float pe_lds[DD][64];
    __shared__ float W_lds[DD * DD];
    __shared__ float hpart[4][64];

    const int tid = threadIdx.x;
    const int blk = blockIdx.x;        // 256 blocks
    const int b  = blk >> 6;
    const int l0 = (blk & 63) * 64;

    {
        const int l = tid & 63;
        const int kb = tid >> 6;
        #pragma unroll
        for (int it = 0; it < 16; ++it) {
            const int k = it * 4 + kb;
            pe_lds[k][l] = pe[((size_t)b * DD + k) * LL + l0 + l];
        }
    }
    #pragma unroll
    for (int it = 0; it < 16; ++it)
        W_lds[it * 256 + tid] = W[it * 256 + tid];
    __syncthreads();

    const int w = tid >> 6;    // wave owns d-range [w*16, w*16+16)
    const int l = tid & 63;    // lane owns one l
    const float SQRT_LOG2E = 1.2011224087864498f;  // sqrt(1/ln2)
    const float scale = SQRT_LOG2E / ls[0];

    float acc[16];
    #pragma unroll
    for (int i = 0; i < 16; ++i) acc[i] = bias[w * 16 + i];

    for (int k4 = 0; k4 < 16; ++k4) {
        const float p0 = pe_lds[k4 * 4 + 0][l];
        const float p1 = pe_lds[k4 * 4 + 1][l];
        const float p2 = pe_lds[k4 * 4 + 2][l];
        const float p3 = pe_lds[k4 * 4 + 3][l];
        #pragma unroll
        for (int i = 0; i < 16; ++i) {
            const float4 wv = *(const float4*)&W_lds[(w * 16 + i) * DD + k4 * 4];
            acc[i] += p0 * wv.x + p1 * wv.y + p2 * wv.z + p3 * wv.w;
        }
    }

    // bf16 round, h accumulated from the ROUNDED values (diagonal consistency)
    unsigned short out16[16];
    float hs = 0.0f;
    #pragma unroll
    for (int i = 0; i < 16; ++i) {
        const float xf = acc[i] * scale;
        const __bf16 bv = (__bf16)xf;
        const float xr = (float)bv;
        hs += xr * xr;
        out16[i] = __builtin_bit_cast(unsigned short, bv);
    }
    {
        __bf16* dst = xs + ((size_t)b * LL + l0 + l) * DD + w * 16;
        *(uint4*)dst       = *(const uint4*)&out16[0];
        *(uint4*)(dst + 8) = *(const uint4*)&out16[8];
    }
    hpart[w][l] = hs;
    __syncthreads();
    if (tid < 64) {
        const float s = hpart[0][tid] + hpart[1][tid] + hpart[2][tid] + hpart[3][tid];
        h[(size_t)b * LL + tid + l0] = 0.5f * s;
    }
}

// Kernel 2: 4096 blocks, 128x128 tile, 4 waves, 64x64 per wave processed as
// four sequential 32x32 quadrants -> live regs ~110 -> 4 waves/SIMD
// (launch_bounds(256,4)) so the exp2/sub epilogue overlaps the store stream.
// out = exp2(min(dot - hi2[r] - hj, lc)) with lc=log2(outputscale) folded in.
__global__ __launch_bounds__(256, 4) void gram_kernel(
    const __bf16* __restrict__ xs,  // [B][L][D]
    const float* __restrict__ h,    // [B][L]
    const float* __restrict__ osc,  // scalar
    float* __restrict__ out)        // [B][L][L]
{
    const int bid = blockIdx.x;       // 4096 = 4 * 32 * 32
    const int b  = bid >> 10;
    const int t  = bid & 1023;
    const int ti = t >> 5, tj = t & 31;

    const int tid  = threadIdx.x;
    const int wid  = tid >> 6;
    const int lane = tid & 63;
    const int lr = lane & 31, lg = lane >> 5;

    const int rows0 = ti * 128 + (wid >> 1) * 64;
    const int cols0 = tj * 128 + (wid & 1) * 64;

    const __bf16* xsb = xs + (size_t)b * LL * DD;
    const float*  hb  = h + (size_t)b * LL;

    const float c  = osc[0];
    const float lc = __builtin_log2f(c);

    #pragma unroll 1
    for (int mt = 0; mt < 2; ++mt) {
        const int r0 = rows0 + mt * 32;

        bf16x8 af[4];
        #pragma unroll
        for (int kk = 0; kk < 4; ++kk)
            af[kk] = *(const bf16x8*)(xsb + (size_t)(r0 + lr) * DD + kk * 16 + lg * 8);

        float hi2[16];
        #pragma unroll
        for (int r = 0; r < 16; ++r)
            hi2[r] = hb[r0 + (r & 3) + 8 * (r >> 2) + 4 * lg] - lc;

        #pragma unroll 1
        for (int nt = 0; nt < 2; ++nt) {
            const int c0 = cols0 + nt * 32;

            // A and B fragments use the IDENTICAL (lane,slot)->k mapping: any
            // HW k-permutation preserves the Gram dot product.
            bf16x8 bg[4];
            #pragma unroll
            for (int kk = 0; kk < 4; ++kk)
                bg[kk] = *(const bf16x8*)(xsb + (size_t)(c0 + lr) * DD + kk * 16 + lg * 8);

            f32x16 acc = (f32x16)(0.0f);
            #pragma unroll
            for (int kk = 0; kk < 4; ++kk)
                acc = __builtin_amdgcn_mfma_f32_32x32x16_bf16(af[kk], bg[kk], acc, 0, 0, 0);

            const int col = c0 + lr;
            const float hj = hb[col];
            // C/D layout: col = lane&31, row = (r&3) + 8*(r>>2) + 4*(lane>>5)
            float* op = out + ((size_t)b * LL + r0 + 4 * lg) * LL + col;
            #pragma unroll
            for (int r = 0; r < 16; ++r) {
                float tt = acc[r] - hi2[r] - hj;   // log2-scaled sq-dist + lc
                tt = fminf(tt, lc);                // clamp(sq,0) + fold of c
                const int rowoff = (r & 3) + 8 * (r >> 2);
                op[(size_t)rowoff * LL] = __builtin_amdgcn_exp2f(tt);
            }
        }
    }
}

extern "C" void kernel_launch(void* const* d_in, const int* in_sizes, int n_in,
                              void* d_out, int out_size, void* d_ws, size_t ws_size,
                              hipStream_t stream) {
    const float* pe   = (const float*)d_in[0];
    const float* W    = (const float*)d_in[1];
    const float* bias = (const float*)d_in[2];
    const float* ls   = (const float*)d_in[3];
    const float* osc  = (const float*)d_in[4];
    float* out = (float*)d_out;

    __bf16* xs = (__bf16*)d_ws;                                       // 2 MiB
    float*  h  = (float*)((char*)d_ws + (size_t)BB * LL * DD * 2);    // 64 KiB

    prep_kernel<<<256, 256, 0, stream>>>(pe, W, bias, ls, xs, h);
    gram_kernel<<<BB * 32 * 32, 256, 0, stream>>>(xs, h, osc, out);
}

// Round 4
// 68.434 us; speedup vs baseline: 1.0964x; 1.0964x over previous
//
#include <hip/hip_runtime.h>

using bf16x8 = __attribute__((ext_vector_type(8))) __bf16;
using f32x16 = __attribute__((ext_vector_type(16))) float;

#define BB 4
#define DD 64
#define LL 4096

// Kernel 1: x[b,l,d] = sum_k pe[b,k,l]*W[d,k] + bias[d];
// xs = bf16(x * sqrt(log2e)/ls)  (log2-domain pre-scale);
// h = 0.5*sum(xs_rounded^2)  -> MFMA dot - hi - hj is directly the exp2 arg.
__global__ __launch_bounds__(256) void prep_kernel(
    const float* __restrict__ pe,   // [B][D][L]
    const float* __restrict__ W,    // [D][D] row-major (out,in)
    const float* __restrict__ bias, // [D]
    const float* __restrict__ ls,   // scalar
    __bf16* __restrict__ xs,        // [B][L][D]
    float* __restrict__ h)          // [B][L]
{
    __shared__ float pe_lds[DD][64];
    __shared__ float W_lds[DD * DD];
    __shared__ float hpart[4][64];

    const int tid = threadIdx.x;
    const int blk = blockIdx.x;        // 256 blocks
    const int b  = blk >> 6;
    const int l0 = (blk & 63) * 64;

    {
        const int l = tid & 63;
        const int kb = tid >> 6;
        #pragma unroll
        for (int it = 0; it < 16; ++it) {
            const int k = it * 4 + kb;
            pe_lds[k][l] = pe[((size_t)b * DD + k) * LL + l0 + l];
        }
    }
    #pragma unroll
    for (int it = 0; it < 16; ++it)
        W_lds[it * 256 + tid] = W[it * 256 + tid];
    __syncthreads();

    const int w = tid >> 6;    // wave owns d-range [w*16, w*16+16)
    const int l = tid & 63;    // lane owns one l
    const float SQRT_LOG2E = 1.2011224087864498f;  // sqrt(1/ln2)
    const float scale = SQRT_LOG2E / ls[0];

    float acc[16];
    #pragma unroll
    for (int i = 0; i < 16; ++i) acc[i] = bias[w * 16 + i];

    for (int k4 = 0; k4 < 16; ++k4) {
        const float p0 = pe_lds[k4 * 4 + 0][l];
        const float p1 = pe_lds[k4 * 4 + 1][l];
        const float p2 = pe_lds[k4 * 4 + 2][l];
        const float p3 = pe_lds[k4 * 4 + 3][l];
        #pragma unroll
        for (int i = 0; i < 16; ++i) {
            const float4 wv = *(const float4*)&W_lds[(w * 16 + i) * DD + k4 * 4];
            acc[i] += p0 * wv.x + p1 * wv.y + p2 * wv.z + p3 * wv.w;
        }
    }

    // bf16 round, h accumulated from the ROUNDED values (diagonal consistency)
    unsigned short out16[16];
    float hs = 0.0f;
    #pragma unroll
    for (int i = 0; i < 16; ++i) {
        const float xf = acc[i] * scale;
        const __bf16 bv = (__bf16)xf;
        const float xr = (float)bv;
        hs += xr * xr;
        out16[i] = __builtin_bit_cast(unsigned short, bv);
    }
    {
        __bf16* dst = xs + ((size_t)b * LL + l0 + l) * DD + w * 16;
        *(uint4*)dst       = *(const uint4*)&out16[0];
        *(uint4*)(dst + 8) = *(const uint4*)&out16[8];
    }
    hpart[w][l] = hs;
    __syncthreads();
    if (tid < 64) {
        const float s = hpart[0][tid] + hpart[1][tid] + hpart[2][tid] + hpart[3][tid];
        h[(size_t)b * LL + tid + l0] = 0.5f * s;
    }
}

// Kernel 2: 4096 blocks, 32x512 output tile per block (tj-inner ordering so
// 8 consecutive blocks fill a contiguous 512KB row-stripe -> DRAM page
// locality like the fill kernel). 4 waves side-by-side in cols: 32x128 per
// wave. R0 structure: all fragments upfront, 4 independent MFMA chains,
// bursty epilogue, plain dword stores, no launch_bounds cap.
__global__ __launch_bounds__(256) void gram_kernel(
    const __bf16* __restrict__ xs,  // [B][L][D]
    const float* __restrict__ h,    // [B][L]
    const float* __restrict__ osc,  // scalar
    float* __restrict__ out)        // [B][L][L]
{
    const int bid = blockIdx.x;       // 4096 = 4 * 128 * 8
    const int b  = bid >> 10;
    const int t  = bid & 1023;
    const int ti = t >> 3;            // 128 row-tiles of 32
    const int tj = t & 7;             // 8 col-tiles of 512

    const int tid  = threadIdx.x;
    const int wid  = tid >> 6;
    const int lane = tid & 63;
    const int lr = lane & 31, lg = lane >> 5;

    const int rows0 = ti * 32;                  // shared by all 4 waves
    const int cols0 = tj * 512 + wid * 128;     // wave's 128-col strip

    const __bf16* xsb = xs + (size_t)b * LL * DD;
    const float*  hb  = h + (size_t)b * LL;

    const float c  = osc[0];
    const float lc = __builtin_log2f(c);

    // A and B fragments use the IDENTICAL (lane,slot)->k mapping: any HW
    // k-permutation preserves the Gram dot product.
    bf16x8 af[4], bg[4][4];
    #pragma unroll
    for (int kk = 0; kk < 4; ++kk)
        af[kk] = *(const bf16x8*)(xsb + (size_t)(rows0 + lr) * DD + kk * 16 + lg * 8);
    #pragma unroll
    for (int nt = 0; nt < 4; ++nt)
        #pragma unroll
        for (int kk = 0; kk < 4; ++kk)
            bg[nt][kk] = *(const bf16x8*)(xsb + (size_t)(cols0 + nt * 32 + lr) * DD + kk * 16 + lg * 8);

    f32x16 acc[4];
    #pragma unroll
    for (int nt = 0; nt < 4; ++nt) acc[nt] = (f32x16)(0.0f);

    #pragma unroll
    for (int kk = 0; kk < 4; ++kk)
        #pragma unroll
        for (int nt = 0; nt < 4; ++nt)
            acc[nt] = __builtin_amdgcn_mfma_f32_32x32x16_bf16(af[kk], bg[nt][kk], acc[nt], 0, 0, 0);

    // C/D layout (verified): col = lane&31, row = (r&3) + 8*(r>>2) + 4*(lane>>5)
    float hi2[16];
    #pragma unroll
    for (int r = 0; r < 16; ++r)
        hi2[r] = hb[rows0 + (r & 3) + 8 * (r >> 2) + 4 * lg] - lc;

    #pragma unroll
    for (int nt = 0; nt < 4; ++nt) {
        const int col = cols0 + nt * 32 + lr;
        const float hj = hb[col];
        float* op = out + ((size_t)b * LL + rows0 + 4 * lg) * LL + col;
        #pragma unroll
        for (int r = 0; r < 16; ++r) {
            float tt = acc[nt][r] - hi2[r] - hj;   // log2-scaled sq-dist, lc folded
            tt = fminf(tt, lc);                    // clamp(sq,0) + outputscale
            const int rowoff = (r & 3) + 8 * (r >> 2);
            op[(size_t)rowoff * LL] = __builtin_amdgcn_exp2f(tt);
        }
    }
}

extern "C" void kernel_launch(void* const* d_in, const int* in_sizes, int n_in,
                              void* d_out, int out_size, void* d_ws, size_t ws_size,
                              hipStream_t stream) {
    const float* pe   = (const float*)d_in[0];
    const float* W    = (const float*)d_in[1];
    const float* bias = (const float*)d_in[2];
    const float* ls   = (const float*)d_in[3];
    const float* osc  = (const float*)d_in[4];
    float* out = (float*)d_out;

    __bf16* xs = (__bf16*)d_ws;                                       // 2 MiB
    float*  h  = (float*)((char*)d_ws + (size_t)BB * LL * DD * 2);    // 64 KiB

    prep_kernel<<<256, 256, 0, stream>>>(pe, W, bias, ls, xs, h);
    gram_kernel<<<BB * 32 * 32, 256, 0, stream>>>(xs, h, osc, out);
}

// Round 5
// 61.300 us; speedup vs baseline: 1.2240x; 1.1164x over previous
//
#include <hip/hip_runtime.h>

using bf16x8 = __attribute__((ext_vector_type(8))) __bf16;
using f32x16 = __attribute__((ext_vector_type(16))) float;

#define BB 4
#define DD 64
#define LL 4096

// Kernel 1: x[b,l,d] = sum_k pe[b,k,l]*W[d,k] + bias[d];
// xs = bf16(x * sqrt(log2e)/ls)  (log2-domain pre-scale);
// h = 0.5*sum(xs_rounded^2)  -> MFMA dot - hi - hj is directly the exp2 arg.
__global__ __launch_bounds__(256) void prep_kernel(
    const float* __restrict__ pe,   // [B][D][L]
    const float* __restrict__ W,    // [D][D] row-major (out,in)
    const float* __restrict__ bias, // [D]
    const float* __restrict__ ls,   // scalar
    __bf16* __restrict__ xs,        // [B][L][D]
    float* __restrict__ h)          // [B][L]
{
    __shared__ float pe_lds[DD][64];
    __shared__ float W_lds[DD * DD];
    __shared__ float hpart[4][64];

    const int tid = threadIdx.x;
    const int blk = blockIdx.x;        // 256 blocks
    const int b  = blk >> 6;
    const int l0 = (blk & 63) * 64;

    {
        const int l = tid & 63;
        const int kb = tid >> 6;
        #pragma unroll
        for (int it = 0; it < 16; ++it) {
            const int k = it * 4 + kb;
            pe_lds[k][l] = pe[((size_t)b * DD + k) * LL + l0 + l];
        }
    }
    #pragma unroll
    for (int it = 0; it < 16; ++it)
        W_lds[it * 256 + tid] = W[it * 256 + tid];
    __syncthreads();

    const int w = tid >> 6;    // wave owns d-range [w*16, w*16+16)
    const int l = tid & 63;    // lane owns one l
    const float SQRT_LOG2E = 1.2011224087864498f;  // sqrt(1/ln2)
    const float scale = SQRT_LOG2E / ls[0];

    float acc[16];
    #pragma unroll
    for (int i = 0; i < 16; ++i) acc[i] = bias[w * 16 + i];

    for (int k4 = 0; k4 < 16; ++k4) {
        const float p0 = pe_lds[k4 * 4 + 0][l];
        const float p1 = pe_lds[k4 * 4 + 1][l];
        const float p2 = pe_lds[k4 * 4 + 2][l];
        const float p3 = pe_lds[k4 * 4 + 3][l];
        #pragma unroll
        for (int i = 0; i < 16; ++i) {
            const float4 wv = *(const float4*)&W_lds[(w * 16 + i) * DD + k4 * 4];
            acc[i] += p0 * wv.x + p1 * wv.y + p2 * wv.z + p3 * wv.w;
        }
    }

    // bf16 round, h accumulated from the ROUNDED values (diagonal consistency)
    unsigned short out16[16];
    float hs = 0.0f;
    #pragma unroll
    for (int i = 0; i < 16; ++i) {
        const float xf = acc[i] * scale;
        const __bf16 bv = (__bf16)xf;
        const float xr = (float)bv;
        hs += xr * xr;
        out16[i] = __builtin_bit_cast(unsigned short, bv);
    }
    {
        __bf16* dst = xs + ((size_t)b * LL + l0 + l) * DD + w * 16;
        *(uint4*)dst       = *(const uint4*)&out16[0];
        *(uint4*)(dst + 8) = *(const uint4*)&out16[8];
    }
    hpart[w][l] = hs;
    __syncthreads();
    if (tid < 64) {
        const float s = hpart[0][tid] + hpart[1][tid] + hpart[2][tid] + hpart[3][tid];
        h[(size_t)b * LL + tid + l0] = 0.5f * s;
    }
}

// Kernel 2: EXACT R0 geometry (measured best: 63.5us): 4096 blocks, 128x128
// tile, 4 waves, 64x64 per wave, all fragments upfront, no launch_bounds.
// Single experimental knob vs R0: NONTEMPORAL stores (keep the dead-on-
// arrival 256MB output stream from evicting the 2MB xs set out of L2).
// Epilogue math carried from R2/R3 (neutral, fewer ops): log2-domain dot,
// lc = log2(outputscale) folded into the clamp.
__global__ __launch_bounds__(256) void gram_kernel(
    const __bf16* __restrict__ xs,  // [B][L][D]
    const float* __restrict__ h,    // [B][L]
    const float* __restrict__ osc,  // scalar
    float* __restrict__ out)        // [B][L][L]
{
    const int bid = blockIdx.x;       // 4096 = 4 * 32 * 32
    const int b  = bid >> 10;
    const int t  = bid & 1023;
    const int ti = t >> 5, tj = t & 31;

    const int tid  = threadIdx.x;
    const int wid  = tid >> 6;
    const int lane = tid & 63;
    const int lr = lane & 31, lg = lane >> 5;

    const int rows0 = ti * 128 + (wid >> 1) * 64;
    const int cols0 = tj * 128 + (wid & 1) * 64;

    const __bf16* xsb = xs + (size_t)b * LL * DD;
    const float*  hb  = h + (size_t)b * LL;

    // A and B fragments use the IDENTICAL (lane,slot)->k mapping: any HW
    // k-permutation preserves the Gram dot product.
    bf16x8 af[2][4], bg[2][4];
    #pragma unroll
    for (int mt = 0; mt < 2; ++mt)
        #pragma unroll
        for (int kk = 0; kk < 4; ++kk)
            af[mt][kk] = *(const bf16x8*)(xsb + (size_t)(rows0 + mt * 32 + lr) * DD + kk * 16 + lg * 8);
    #pragma unroll
    for (int nt = 0; nt < 2; ++nt)
        #pragma unroll
        for (int kk = 0; kk < 4; ++kk)
            bg[nt][kk] = *(const bf16x8*)(xsb + (size_t)(cols0 + nt * 32 + lr) * DD + kk * 16 + lg * 8);

    f32x16 acc[2][2];
    #pragma unroll
    for (int mt = 0; mt < 2; ++mt)
        #pragma unroll
        for (int nt = 0; nt < 2; ++nt)
            acc[mt][nt] = (f32x16)(0.0f);

    #pragma unroll
    for (int kk = 0; kk < 4; ++kk)
        #pragma unroll
        for (int mt = 0; mt < 2; ++mt)
            #pragma unroll
            for (int nt = 0; nt < 2; ++nt)
                acc[mt][nt] = __builtin_amdgcn_mfma_f32_32x32x16_bf16(
                    af[mt][kk], bg[nt][kk], acc[mt][nt], 0, 0, 0);

    const float c  = osc[0];
    const float lc = __builtin_log2f(c);

    #pragma unroll
    for (int mt = 0; mt < 2; ++mt) {
        // C/D layout (verified): col = lane&31, row = (r&3)+8*(r>>2)+4*(lane>>5)
        float hi2[16];
        #pragma unroll
        for (int r = 0; r < 16; ++r)
            hi2[r] = hb[rows0 + mt * 32 + (r & 3) + 8 * (r >> 2) + 4 * lg] - lc;
        #pragma unroll
        for (int nt = 0; nt < 2; ++nt) {
            const int col = cols0 + nt * 32 + lr;
            const float hj = hb[col];
            float* op = out + ((size_t)b * LL + rows0 + mt * 32 + 4 * lg) * LL + col;
            #pragma unroll
            for (int r = 0; r < 16; ++r) {
                float tt = acc[mt][nt][r] - hi2[r] - hj;  // log2-scaled
                tt = fminf(tt, lc);                       // clamp + outputscale
                const int rowoff = (r & 3) + 8 * (r >> 2);
                __builtin_nontemporal_store(__builtin_amdgcn_exp2f(tt),
                                            &op[(size_t)rowoff * LL]);
            }
        }
    }
}

extern "C" void kernel_launch(void* const* d_in, const int* in_sizes, int n_in,
                              void* d_out, int out_size, void* d_ws, size_t ws_size,
                              hipStream_t stream) {
    const float* pe   = (const float*)d_in[0];
    const float* W    = (const float*)d_in[1];
    const float* bias = (const float*)d_in[2];
    const float* ls   = (const float*)d_in[3];
    const float* osc  = (const float*)d_in[4];
    float* out = (float*)d_out;

    __bf16* xs = (__bf16*)d_ws;                                       // 2 MiB
    float*  h  = (float*)((char*)d_ws + (size_t)BB * LL * DD * 2);    // 64 KiB

    prep_kernel<<<256, 256, 0, stream>>>(pe, W, bias, ls, xs, h);
    gram_kernel<<<BB * 32 * 32, 256, 0, stream>>>(xs, h, osc, out);
}